// Round 1
// baseline (446.785 us; speedup 1.0000x reference)
//
#include <hip/hip_runtime.h>
#include <stdint.h>

#define NROWS 16384
#define NCOLS 4096
#define KSEL  1638            // int(0.1 * 16384)
#define COLG  64              // columns per histogram block
#define ROWG  8               // row groups
#define RPB   (NROWS / ROWG)  // 2048 rows per block
#define CAND_CAP 256

// order-preserving fp32 -> uint32 (larger u <=> larger float)
__device__ __forceinline__ uint32_t fmono(float f) {
    uint32_t b = __float_as_uint(f);
    return (b & 0x80000000u) ? ~b : (b | 0x80000000u);
}

// K1: per-column histogram of top 8 bits of u.
__global__ __launch_bounds__(256) void k_hist1(const float4* __restrict__ x4,
                                               uint32_t* __restrict__ hist1) {
    __shared__ uint32_t h[COLG * 256];   // h[col_local*256 + bin], 64 KiB
    int tid = threadIdx.x;
    for (int i = tid; i < COLG * 256; i += 256) h[i] = 0;
    __syncthreads();
    int cg = blockIdx.x & 63;            // NCOLS/COLG = 64 col groups
    int rg = blockIdx.x >> 6;            // ROWG row groups
    int c0 = cg * COLG;
    int r0 = rg * RPB;
    int q  = tid & 15;                   // float4 slot within 64-col group
    int lr = tid >> 4;                   // 0..15
    for (int r = lr; r < RPB; r += 16) {
        float4 v = x4[(size_t)(r0 + r) * (NCOLS / 4) + (c0 >> 2) + q];
        uint32_t u0 = fmono(v.x), u1 = fmono(v.y), u2 = fmono(v.z), u3 = fmono(v.w);
        atomicAdd(&h[(q * 4 + 0) * 256 + (u0 >> 24)], 1u);
        atomicAdd(&h[(q * 4 + 1) * 256 + (u1 >> 24)], 1u);
        atomicAdd(&h[(q * 4 + 2) * 256 + (u2 >> 24)], 1u);
        atomicAdd(&h[(q * 4 + 3) * 256 + (u3 >> 24)], 1u);
    }
    __syncthreads();
    for (int i = tid; i < COLG * 256; i += 256) {
        uint32_t v = h[i];
        if (v) {
            int cl  = i >> 8;
            int bin = i & 255;
            atomicAdd(&hist1[(size_t)(c0 + cl) * 256 + bin], v);
        }
    }
}

// K2: scan hist1 top-down, find boundary bin b1 and rank k1 within it.
__global__ void k_scan1(const uint32_t* __restrict__ hist1,
                        uint32_t* __restrict__ meta1) {
    int col = blockIdx.x * blockDim.x + threadIdx.x;
    if (col >= NCOLS) return;
    const uint32_t* h = hist1 + (size_t)col * 256;
    uint32_t cum = 0, b1 = 0, k1 = 0;
    for (int b = 255; b >= 0; --b) {
        uint32_t c = h[b];
        if (cum + c >= (uint32_t)KSEL) { b1 = (uint32_t)b; k1 = KSEL - cum; break; }
        cum += c;
    }
    meta1[col] = (b1 << 16) | k1;
}

// K3: second-level histogram (bits 16..23) of elements whose top byte == b1.
__global__ __launch_bounds__(256) void k_hist2(const float4* __restrict__ x4,
                                               const uint32_t* __restrict__ meta1,
                                               uint32_t* __restrict__ hist2) {
    __shared__ uint32_t h[COLG * 256];
    int tid = threadIdx.x;
    for (int i = tid; i < COLG * 256; i += 256) h[i] = 0;
    __syncthreads();
    int cg = blockIdx.x & 63;
    int rg = blockIdx.x >> 6;
    int c0 = cg * COLG;
    int r0 = rg * RPB;
    int q  = tid & 15;
    int lr = tid >> 4;
    uint32_t b1_0 = meta1[c0 + q * 4 + 0] >> 16;
    uint32_t b1_1 = meta1[c0 + q * 4 + 1] >> 16;
    uint32_t b1_2 = meta1[c0 + q * 4 + 2] >> 16;
    uint32_t b1_3 = meta1[c0 + q * 4 + 3] >> 16;
    for (int r = lr; r < RPB; r += 16) {
        float4 v = x4[(size_t)(r0 + r) * (NCOLS / 4) + (c0 >> 2) + q];
        uint32_t u0 = fmono(v.x), u1 = fmono(v.y), u2 = fmono(v.z), u3 = fmono(v.w);
        if ((u0 >> 24) == b1_0) atomicAdd(&h[(q * 4 + 0) * 256 + ((u0 >> 16) & 255)], 1u);
        if ((u1 >> 24) == b1_1) atomicAdd(&h[(q * 4 + 1) * 256 + ((u1 >> 16) & 255)], 1u);
        if ((u2 >> 24) == b1_2) atomicAdd(&h[(q * 4 + 2) * 256 + ((u2 >> 16) & 255)], 1u);
        if ((u3 >> 24) == b1_3) atomicAdd(&h[(q * 4 + 3) * 256 + ((u3 >> 16) & 255)], 1u);
    }
    __syncthreads();
    for (int i = tid; i < COLG * 256; i += 256) {
        uint32_t v = h[i];
        if (v) {
            int cl  = i >> 8;
            int bin = i & 255;
            atomicAdd(&hist2[(size_t)(c0 + cl) * 256 + bin], v);
        }
    }
}

// K4: scan hist2 top-down within b1 -> 16-bit prefix and rank k2.
__global__ void k_scan2(const uint32_t* __restrict__ hist2,
                        const uint32_t* __restrict__ meta1,
                        uint32_t* __restrict__ meta2) {
    int col = blockIdx.x * blockDim.x + threadIdx.x;
    if (col >= NCOLS) return;
    uint32_t m1 = meta1[col];
    uint32_t b1 = m1 >> 16, k1 = m1 & 0xFFFFu;
    const uint32_t* h = hist2 + (size_t)col * 256;
    uint32_t cum = 0, b2 = 0, k2 = k1;
    for (int b = 255; b >= 0; --b) {
        uint32_t c = h[b];
        if (cum + c >= k1) { b2 = (uint32_t)b; k2 = k1 - cum; break; }
        cum += c;
    }
    meta2[col] = (((b1 << 8) | b2) << 16) | k2;
}

// K5: compact candidates (16-bit prefix match) into per-column lists.
__global__ __launch_bounds__(256) void k_compact(const float4* __restrict__ x4,
                                                 const uint32_t* __restrict__ meta2,
                                                 uint32_t* __restrict__ cnt,
                                                 uint32_t* __restrict__ cand) {
    size_t stride = (size_t)gridDim.x * blockDim.x;
    size_t total  = (size_t)NROWS * NCOLS / 4;
    const uint4* m4 = (const uint4*)meta2;
    for (size_t i = (size_t)blockIdx.x * blockDim.x + threadIdx.x; i < total; i += stride) {
        float4 v = x4[i];
        uint32_t r  = (uint32_t)(i / (NCOLS / 4));
        int      q  = (int)(i % (NCOLS / 4));
        int      c4 = q * 4;
        uint4    mm = m4[q];
        uint32_t us[4] = {fmono(v.x), fmono(v.y), fmono(v.z), fmono(v.w)};
        uint32_t ms[4] = {mm.x, mm.y, mm.z, mm.w};
        #pragma unroll
        for (int j = 0; j < 4; ++j) {
            if ((us[j] >> 16) == (ms[j] >> 16)) {
                int c = c4 + j;
                uint32_t pos = atomicAdd(&cnt[c], 1u);
                if (pos < CAND_CAP)
                    cand[(size_t)c * CAND_CAP + pos] = (r << 16) | (us[j] & 0xFFFFu);
            }
        }
    }
}

// K6: per-column exact select among candidates -> full threshold t_u and
// row cutoff R_cut reproducing stable-sort tie handling.
__global__ void k_select(const uint32_t* __restrict__ meta2,
                         const uint32_t* __restrict__ cnt,
                         const uint32_t* __restrict__ cand,
                         uint32_t* __restrict__ tu,
                         uint32_t* __restrict__ rcut) {
    int col = blockIdx.x * blockDim.x + threadIdx.x;
    if (col >= NCOLS) return;
    uint32_t m = meta2[col];
    uint32_t prefix = m >> 16, k2 = m & 0xFFFFu;
    uint32_t n = cnt[col];
    if (n > CAND_CAP) n = CAND_CAP;
    const uint32_t* cd = cand + (size_t)col * CAND_CAP;
    uint32_t t_low = 0, g = 0, e = 0;
    for (uint32_t i = 0; i < n; ++i) {
        uint32_t li = cd[i] & 0xFFFFu;
        uint32_t gi = 0, ei = 0;
        for (uint32_t j = 0; j < n; ++j) {
            uint32_t lj = cd[j] & 0xFFFFu;
            gi += (lj > li);
            ei += (lj == li);
        }
        if (gi < k2 && gi + ei >= k2) { t_low = li; g = gi; e = ei; break; }
    }
    uint32_t need = k2 - g;   // 1..e equals must be zeroed, smallest rows first
    uint32_t R;
    if (need >= e) {
        R = NROWS;            // zero all equals
    } else {
        R = 0;
        for (uint32_t i = 0; i < n; ++i) {
            uint32_t w = cd[i];
            if ((w & 0xFFFFu) != t_low) continue;
            uint32_t r = w >> 16;
            uint32_t rank = 0;
            for (uint32_t j = 0; j < n; ++j) {
                uint32_t wj = cd[j];
                if ((wj & 0xFFFFu) == t_low && (wj >> 16) < r) rank++;
            }
            if (rank == need - 1) { R = r + 1; break; }
        }
    }
    tu[col]   = (prefix << 16) | t_low;
    rcut[col] = R;
}

// K7: elementwise map.
__global__ __launch_bounds__(256) void k_map(const float4* __restrict__ x4,
                                             const uint32_t* __restrict__ tu,
                                             const uint32_t* __restrict__ rcut,
                                             float4* __restrict__ out4) {
    size_t stride = (size_t)gridDim.x * blockDim.x;
    size_t total  = (size_t)NROWS * NCOLS / 4;
    const uint4* t4 = (const uint4*)tu;
    const uint4* r4 = (const uint4*)rcut;
    for (size_t i = (size_t)blockIdx.x * blockDim.x + threadIdx.x; i < total; i += stride) {
        float4 v = x4[i];
        uint32_t r = (uint32_t)(i / (NCOLS / 4));
        int      q = (int)(i % (NCOLS / 4));
        uint4 tt = t4[q];
        uint4 rr = r4[q];
        float4 o;
        uint32_t u;
        u = fmono(v.x); o.x = (u > tt.x || (u == tt.x && r < rr.x)) ? 0.0f : v.x;
        u = fmono(v.y); o.y = (u > tt.y || (u == tt.y && r < rr.y)) ? 0.0f : v.y;
        u = fmono(v.z); o.z = (u > tt.z || (u == tt.z && r < rr.z)) ? 0.0f : v.z;
        u = fmono(v.w); o.w = (u > tt.w || (u == tt.w && r < rr.w)) ? 0.0f : v.w;
        out4[i] = o;
    }
}

extern "C" void kernel_launch(void* const* d_in, const int* in_sizes, int n_in,
                              void* d_out, int out_size, void* d_ws, size_t ws_size,
                              hipStream_t stream) {
    const float* x = (const float*)d_in[0];
    float* out = (float*)d_out;

    // Big scratch lives in d_out (dead before K7 rewrites it); d_ws holds
    // only 80 KiB of per-column metadata (survives until K7).
    uint32_t* hist1 = (uint32_t*)d_out;                 // NCOLS*256 (4 MiB)
    uint32_t* hist2 = hist1 + (size_t)NCOLS * 256;      // NCOLS*256 (4 MiB)
    uint32_t* cand  = hist2 + (size_t)NCOLS * 256;      // NCOLS*CAND_CAP (4 MiB)

    uint32_t* cnt   = (uint32_t*)d_ws;                  // NCOLS
    uint32_t* meta1 = cnt   + NCOLS;                    // NCOLS
    uint32_t* meta2 = meta1 + NCOLS;                    // NCOLS
    uint32_t* tu    = meta2 + NCOLS;                    // NCOLS
    uint32_t* rcut  = tu    + NCOLS;                    // NCOLS

    hipMemsetAsync(hist1, 0, (size_t)2 * NCOLS * 256 * sizeof(uint32_t), stream);
    hipMemsetAsync(cnt,   0, (size_t)NCOLS * sizeof(uint32_t), stream);

    const float4* x4 = (const float4*)x;
    k_hist1  <<<COLG * ROWG,           256, 0, stream>>>(x4, hist1);
    k_scan1  <<<NCOLS / 256,           256, 0, stream>>>(hist1, meta1);
    k_hist2  <<<COLG * ROWG,           256, 0, stream>>>(x4, meta1, hist2);
    k_scan2  <<<NCOLS / 256,           256, 0, stream>>>(hist2, meta1, meta2);
    k_compact<<<4096,                  256, 0, stream>>>(x4, meta2, cnt, cand);
    k_select <<<NCOLS / 256,           256, 0, stream>>>(meta2, cnt, cand, tu, rcut);
    k_map    <<<4096,                  256, 0, stream>>>(x4, tu, rcut, (float4*)out);
}